// Round 4
// baseline (288.002 us; speedup 1.0000x reference)
//
#include <hip/hip_runtime.h>

// PyramidROIAlign: B=2, N=1000, C=256, pool 7x7, f32.
// PROBE ROUND: cell-per-wave kernel (round-1 structure, best ILP), launched
// TWICE to measure kernel time k via dur_us delta (dur = F_harness + 2k,
// round-1 gave F + k = 250.8). Second launch writes identical output —
// idempotent, graph-capture safe.
//
// One 64-lane wave per pool cell (box, py, px); lane handles 4 channels.
// 4 independent coalesced float4 corner loads + 1 nontemporal float4 store.

#define POOL 7
#define CCH 256

typedef float f4 __attribute__((ext_vector_type(4)));

__global__ __launch_bounds__(256) void roi_align_kernel(
    const float* __restrict__ boxes,   // [B*N, 4] y1,x1,y2,x2
    const float* __restrict__ ish,     // [2]
    const float* __restrict__ P2,
    const float* __restrict__ P3,
    const float* __restrict__ P4,
    const float* __restrict__ P5,
    float* __restrict__ out,           // [B*N, 7, 7, C]
    int n_cells, int N)
{
    int cell = blockIdx.x * 4 + (threadIdx.x >> 6);
    if (cell >= n_cells) return;
    int lane = threadIdx.x & 63;

    int px  = cell % POOL;
    int t   = cell / POOL;
    int py  = t % POOL;
    int n   = t / POOL;          // flat box index in [0, B*N)
    int b   = n / N;             // batch index

    float y1 = boxes[n * 4 + 0];
    float x1 = boxes[n * 4 + 1];
    float y2 = boxes[n * 4 + 2];
    float x2 = boxes[n * 4 + 3];
    float h = y2 - y1;
    float w = x2 - x1;

    // compute_roi_level — same expression order as reference (rintf = np.round).
    float area = ish[0] * ish[1];
    float lvl  = log2f(sqrtf(h * w) / (224.0f / sqrtf(area)));
    float Lf   = fminf(5.0f, fmaxf(2.0f, 4.0f + rintf(lvl)));
    int   L    = (int)Lf;

    const float* fmap;
    int H;
    if (L == 2)      { fmap = P2; H = 256; }
    else if (L == 3) { fmap = P3; H = 128; }
    else if (L == 4) { fmap = P4; H = 64;  }
    else             { fmap = P5; H = 32;  }
    int W = H;

    float gy = (float)py * (1.0f / (POOL - 1));
    float gx = (float)px * (1.0f / (POOL - 1));
    float in_y = (y1 + h * gy) * (float)(H - 1);
    float in_x = (x1 + w * gx) * (float)(W - 1);
    float y0f = floorf(in_y);
    float x0f = floorf(in_x);
    float wy = in_y - y0f;
    float wx = in_x - x0f;
    int y0  = min(max((int)y0f, 0), H - 1);
    int y1i = min(y0 + 1, H - 1);
    int x0  = min(max((int)x0f, 0), W - 1);
    int x1i = min(x0 + 1, W - 1);

    size_t base = (size_t)b * H * W * CCH;
    int c = lane * 4;
    const float* ptl = fmap + base + ((size_t)y0  * W + x0 ) * CCH + c;
    const float* ptr = fmap + base + ((size_t)y0  * W + x1i) * CCH + c;
    const float* pbl = fmap + base + ((size_t)y1i * W + x0 ) * CCH + c;
    const float* pbr = fmap + base + ((size_t)y1i * W + x1i) * CCH + c;

    // 4 independent loads — compiler issues all before the first use.
    f4 tl = *(const f4*)ptl;
    f4 tr = *(const f4*)ptr;
    f4 bl = *(const f4*)pbl;
    f4 br = *(const f4*)pbr;

    f4 top = tl + (tr - tl) * wx;
    f4 bot = bl + (br - bl) * wx;
    f4 o   = top + (bot - top) * wy;

    __builtin_nontemporal_store(o, (f4*)(out + (size_t)cell * CCH + c));
}

extern "C" void kernel_launch(void* const* d_in, const int* in_sizes, int n_in,
                              void* d_out, int out_size, void* d_ws, size_t ws_size,
                              hipStream_t stream)
{
    const float* boxes = (const float*)d_in[0];
    const float* ish   = (const float*)d_in[1];
    const float* P2    = (const float*)d_in[2];
    const float* P3    = (const float*)d_in[3];
    const float* P4    = (const float*)d_in[4];
    const float* P5    = (const float*)d_in[5];
    float* out = (float*)d_out;

    int total_boxes = in_sizes[0] / 4;                  // B*N = 2000
    int B = in_sizes[2] / (256 * 256 * CCH);            // P2 is [B,256,256,C]
    int N = total_boxes / B;
    int n_cells = total_boxes * POOL * POOL;            // 98000

    int blocks = (n_cells + 3) / 4;                     // 4 cells (waves) per block

    // PROBE: launch twice (identical work, idempotent). dur_us - 250.8 ≈ one
    // kernel's duration. Remove the second launch once k is known.
    roi_align_kernel<<<blocks, 256, 0, stream>>>(boxes, ish, P2, P3, P4, P5,
                                                 out, n_cells, N);
    roi_align_kernel<<<blocks, 256, 0, stream>>>(boxes, ish, P2, P3, P4, P5,
                                                 out, n_cells, N);
}